// Round 2
// baseline (403.863 us; speedup 1.0000x reference)
//
#include <hip/hip_runtime.h>
#include <math.h>

#define PI_F 3.14159265358979323846f

// ---------------- fast device math ----------------
__device__ __forceinline__ float sigm_f(float x) {
    return __fdividef(1.0f, 1.0f + __expf(-x));
}
__device__ __forceinline__ float tanh_f(float x) {
    float xc = fminf(fmaxf(x, -9.0f), 9.0f);
    float e = __expf(2.0f * xc);
    return 1.0f - __fdividef(2.0f, e + 1.0f);
}

// ============================================================
// Kernel 1: 2-layer GRU over reversed action sequence + encoder head.
// 128 threads = 4 samples x 32 hidden-lanes. Weights staged to LDS
// transposed + gate-interleaved: w[input][unit*3 + gate].
// Recurrence accumulators split 2-way -> 6 independent FMA chains.
// ============================================================
__global__ __launch_bounds__(128)
void gru_kernel(const float* __restrict__ act,
                const float* __restrict__ Wih0, const float* __restrict__ Whh0,
                const float* __restrict__ bih0, const float* __restrict__ bhh0,
                const float* __restrict__ Wih1, const float* __restrict__ Whh1,
                const float* __restrict__ bih1, const float* __restrict__ bhh1,
                const float* __restrict__ encW, const float* __restrict__ encb,
                float* __restrict__ p_out)
{
    __shared__ float wih0_l[6 * 96];
    __shared__ float whh0_l[32 * 96];
    __shared__ float wih1_l[32 * 96];
    __shared__ float whh1_l[32 * 96];
    __shared__ float enc_l[64];
    __shared__ float xbuf[4 * 32 * 6];
    __shared__ float hbuf0[4][32];
    __shared__ float hbuf1[4][32];

    const int tid = threadIdx.x;

    for (int idx = tid; idx < 96 * 6; idx += 128) {
        int r = idx / 6, c = idx - r * 6;
        wih0_l[c * 96 + (r & 31) * 3 + (r >> 5)] = Wih0[idx];
    }
    for (int idx = tid; idx < 96 * 32; idx += 128) {
        int r = idx >> 5, c = idx & 31;
        int d = c * 96 + (r & 31) * 3 + (r >> 5);
        whh0_l[d] = Whh0[idx];
        wih1_l[d] = Wih1[idx];
        whh1_l[d] = Whh1[idx];
    }
    if (tid < 64) {
        int o = tid >> 5, j = tid & 31;
        enc_l[j * 2 + o] = encW[o * 32 + j];
    }
    {
        const float inv3 = (1.0f / 3.0f);
        int base = blockIdx.x * (4 * 32 * 6);
        for (int idx = tid; idx < 4 * 32 * 6; idx += 128)
            xbuf[idx] = act[base + idx] * inv3;
    }
    __syncthreads();

    const int s = tid >> 5;   // sample within block
    const int j = tid & 31;   // hidden unit
    const int b = blockIdx.x * 4 + s;
    const int j3 = j * 3;

    const float bi0r = bih0[j], bi0z = bih0[32 + j], bi0n = bih0[64 + j];
    const float bh0r = bhh0[j], bh0z = bhh0[32 + j], bh0n = bhh0[64 + j];
    const float bi1r = bih1[j], bi1z = bih1[32 + j], bi1n = bih1[64 + j];
    const float bh1r = bhh1[j], bh1z = bhh1[32 + j], bh1n = bhh1[64 + j];

    float* hb0 = &hbuf0[s][0];
    float* hb1 = &hbuf1[s][0];
    hb0[j] = 0.0f;
    hb1[j] = 0.0f;
    float h0 = 0.0f, h1 = 0.0f;
    const float* xs = &xbuf[s * 192];

    for (int t = 0; t < 32; ++t) {
        const float* xt = &xs[(31 - t) * 6];  // time-reversed input

        // ---- layer 0 ----
        float ar = bi0r, az = bi0z, an = bi0n;
        #pragma unroll
        for (int d = 0; d < 6; ++d) {
            float xv = xt[d];
            const float* w = &wih0_l[d * 96 + j3];
            ar = fmaf(xv, w[0], ar); az = fmaf(xv, w[1], az); an = fmaf(xv, w[2], an);
        }
        float gr0 = bh0r, gz0 = bh0z, gn0 = bh0n;
        float gr1 = 0.0f, gz1 = 0.0f, gn1 = 0.0f;
        #pragma unroll
        for (int i = 0; i < 32; i += 2) {
            float hi0 = hb0[i], hi1 = hb0[i + 1];
            const float* w0 = &whh0_l[i * 96 + j3];
            const float* w1 = &whh0_l[(i + 1) * 96 + j3];
            gr0 = fmaf(hi0, w0[0], gr0); gz0 = fmaf(hi0, w0[1], gz0); gn0 = fmaf(hi0, w0[2], gn0);
            gr1 = fmaf(hi1, w1[0], gr1); gz1 = fmaf(hi1, w1[1], gz1); gn1 = fmaf(hi1, w1[2], gn1);
        }
        float r = sigm_f(ar + gr0 + gr1);
        float z = sigm_f(az + gz0 + gz1);
        float n = tanh_f(an + r * (gn0 + gn1));
        h0 = (1.0f - z) * n + z * h0;
        hb0[j] = h0;

        // ---- layer 1 (input = new h0) ----
        float a1r0 = bi1r, a1z0 = bi1z, a1n0 = bi1n;
        float a1r1 = 0.0f, a1z1 = 0.0f, a1n1 = 0.0f;
        #pragma unroll
        for (int i = 0; i < 32; i += 2) {
            float hi0 = hb0[i], hi1 = hb0[i + 1];
            const float* w0 = &wih1_l[i * 96 + j3];
            const float* w1 = &wih1_l[(i + 1) * 96 + j3];
            a1r0 = fmaf(hi0, w0[0], a1r0); a1z0 = fmaf(hi0, w0[1], a1z0); a1n0 = fmaf(hi0, w0[2], a1n0);
            a1r1 = fmaf(hi1, w1[0], a1r1); a1z1 = fmaf(hi1, w1[1], a1z1); a1n1 = fmaf(hi1, w1[2], a1n1);
        }
        float g1r0 = bh1r, g1z0 = bh1z, g1n0 = bh1n;
        float g1r1 = 0.0f, g1z1 = 0.0f, g1n1 = 0.0f;
        #pragma unroll
        for (int i = 0; i < 32; i += 2) {
            float hi0 = hb1[i], hi1 = hb1[i + 1];
            const float* w0 = &whh1_l[i * 96 + j3];
            const float* w1 = &whh1_l[(i + 1) * 96 + j3];
            g1r0 = fmaf(hi0, w0[0], g1r0); g1z0 = fmaf(hi0, w0[1], g1z0); g1n0 = fmaf(hi0, w0[2], g1n0);
            g1r1 = fmaf(hi1, w1[0], g1r1); g1z1 = fmaf(hi1, w1[1], g1z1); g1n1 = fmaf(hi1, w1[2], g1n1);
        }
        float r1 = sigm_f(a1r0 + a1r1 + g1r0 + g1r1);
        float z1 = sigm_f(a1z0 + a1z1 + g1z0 + g1z1);
        float n1 = tanh_f(a1n0 + a1n1 + r1 * (g1n0 + g1n1));
        h1 = (1.0f - z1) * n1 + z1 * h1;
        hb1[j] = h1;
    }

    // encoder head: p_action[b][o] = sum_j h1_j * encW[o][j] + encb[o]
    float v0 = h1 * enc_l[j * 2 + 0];
    float v1 = h1 * enc_l[j * 2 + 1];
    #pragma unroll
    for (int off = 16; off > 0; off >>= 1) {
        v0 += __shfl_xor(v0, off, 32);
        v1 += __shfl_xor(v1, off, 32);
    }
    if (j == 0) {
        p_out[b * 2 + 0] = v0 + encb[0];
        p_out[b * 2 + 1] = v1 + encb[1];
    }
}

// ============================================================
// Kernel 2: per-(b,t) MLP + Laplace series.
// 256 threads = 4 waves; lane = item (64 items/block), wave w owns
// the k-class k ≡ w (mod 4). Weights are wave-uniform -> s_load.
// ang = pi*k*(t/Tc) = pi*k/2 exactly => only Fr (even k) / Fi (odd k).
// __launch_bounds__(256,2): 256-VGPR budget so h1r/h2r/inp stay in
// registers (VGPR=72 last round proved they were demoted).
// All dot-product chains split 4/8-way for ILP.
// ============================================================
__global__ __launch_bounds__(256, 2)
void mlp_kernel(const float* __restrict__ obs, const float* __restrict__ ts,
                const float* __restrict__ p_act,
                const float* __restrict__ W1, const float* __restrict__ b1,
                const float* __restrict__ W2, const float* __restrict__ b2,
                const float* __restrict__ W3, const float* __restrict__ b3,
                float* __restrict__ out)
{
    __shared__ float h1_lds[64 * 64];
    __shared__ float h2_lds[64 * 64];
    __shared__ float f_lds[4 * 64 * 17];
    __shared__ float scale_lds[64];

    const int tid = threadIdx.x;
    const int w = tid >> 6;     // wave id = k-class
    const int l = tid & 63;     // item lane
    const int item = blockIdx.x * 64 + l;
    const int b = item >> 4;

    const float t = ts[item];
    const float Tc = 2.0f * t;
    const float rTc = __fdividef(1.0f, Tc);
    const float gamma = 0.001f + 4.6051701859880913680f * rTc;  // -ln(0.01)/Tc

    // ---- build inp[85] = [theta_s(33), phi_s(33), p(19)] ----
    float inp[85];
    const float g2 = gamma * gamma;
    const float rg = __fdividef(1.0f, gamma);
    #pragma unroll
    for (int k = 0; k < 33; ++k) {
        float sim = (PI_F * (float)k) * rTc;
        inp[k] = atanf(sim * rg);                        // atan2(s_im, s_re>0)
        float sq = fmaf(sim, sim, g2);
        inp[33 + k] = asinf(__fdividef(sq - 1.0f, sq + 1.0f));
    }
    #pragma unroll
    for (int i = 0; i < 17; ++i) inp[66 + i] = obs[b * 17 + i];
    inp[83] = p_act[b * 2 + 0];
    inp[84] = p_act[b * 2 + 1];

    // ---- H1 (each wave computes 16 of 64 outputs) ----
    {
        const int obase = w * 16;
        for (int oo = 0; oo < 16; ++oo) {
            const int o = obase + oo;
            const float* wr = &W1[o * 85];
            float a0 = b1[o], a1 = 0.0f, a2 = 0.0f, a3 = 0.0f;
            #pragma unroll
            for (int i = 0; i < 84; i += 4) {
                a0 = fmaf(inp[i + 0], wr[i + 0], a0);
                a1 = fmaf(inp[i + 1], wr[i + 1], a1);
                a2 = fmaf(inp[i + 2], wr[i + 2], a2);
                a3 = fmaf(inp[i + 3], wr[i + 3], a3);
            }
            a0 = fmaf(inp[84], wr[84], a0);
            h1_lds[o * 64 + l] = tanh_f((a0 + a1) + (a2 + a3));
        }
    }
    __syncthreads();
    float h1r[64];
    #pragma unroll
    for (int i = 0; i < 64; ++i) h1r[i] = h1_lds[i * 64 + l];

    // ---- H2 ----
    {
        const int obase = w * 16;
        for (int oo = 0; oo < 16; ++oo) {
            const int o = obase + oo;
            const float* wr = &W2[o * 64];
            float a0 = b2[o], a1 = 0.0f, a2 = 0.0f, a3 = 0.0f;
            #pragma unroll
            for (int i = 0; i < 64; i += 4) {
                a0 = fmaf(h1r[i + 0], wr[i + 0], a0);
                a1 = fmaf(h1r[i + 1], wr[i + 1], a1);
                a2 = fmaf(h1r[i + 2], wr[i + 2], a2);
                a3 = fmaf(h1r[i + 3], wr[i + 3], a3);
            }
            h2_lds[o * 64 + l] = tanh_f((a0 + a1) + (a2 + a3));
        }
    }
    __syncthreads();
    float h2r[64];
    #pragma unroll
    for (int i = 0; i < 64; ++i) h2r[i] = h2_lds[i * 64 + l];

    if (w == 3) scale_lds[l] = __expf(gamma * t) * rTc;

    // ---- W3 + series epilogue for k ≡ w (mod 4) ----
    // k%4==0: +Fr (0.5 at k=0); k%4==1: -Fi; k%4==2: -Fr; k%4==3: +Fi
    const float csgn = (w == 1 || w == 2) ? -1.0f : 1.0f;
    for (int o = 0; o < 17; ++o) {
        float facc = 0.0f;
        for (int k = w; k < 33; k += 4) {
            const int rt = o * 33 + k;          // theta row
            const float* wt = &W3[rt * 64];
            const float* wp = &W3[(rt + 561) * 64];  // phi row = (o+17)*33+k
            float at0 = 0.0f, at1 = 0.0f, at2 = 0.0f, at3 = 0.0f;
            float ap0 = 0.0f, ap1 = 0.0f, ap2 = 0.0f, ap3 = 0.0f;
            #pragma unroll
            for (int i = 0; i < 64; i += 4) {
                at0 = fmaf(h2r[i + 0], wt[i + 0], at0);
                at1 = fmaf(h2r[i + 1], wt[i + 1], at1);
                at2 = fmaf(h2r[i + 2], wt[i + 2], at2);
                at3 = fmaf(h2r[i + 3], wt[i + 3], at3);
                ap0 = fmaf(h2r[i + 0], wp[i + 0], ap0);
                ap1 = fmaf(h2r[i + 1], wp[i + 1], ap1);
                ap2 = fmaf(h2r[i + 2], wp[i + 2], ap2);
                ap3 = fmaf(h2r[i + 3], wp[i + 3], ap3);
            }
            float at = b3[rt] + ((at0 + at1) + (at2 + at3));
            float ap = b3[rt + 561] + ((ap0 + ap1) + (ap2 + ap3));
            float theta = tanh_f(at) * PI_F;
            float phi   = tanh_f(ap) * (0.5f * PI_F);
            float sph = __sinf(phi), cph = __cosf(phi);
            float rd = __fdividef(1.0f, 1.0f - sph);
            float tr = (w == 0 || w == 2) ? __cosf(theta) : __sinf(theta);
            float wk = (k == 0) ? 0.5f : 1.0f;
            facc = fmaf(csgn * wk, tr * cph * rd, facc);
        }
        f_lds[(w * 64 + l) * 17 + o] = facc;
    }
    __syncthreads();

    // ---- reduce 4 k-class partials, scale, write out ----
    const int base_item = blockIdx.x * 64;
    for (int idx = tid; idx < 64 * 17; idx += 256) {
        const int li = idx / 17;
        const int o  = idx - li * 17;
        float tot = f_lds[li * 17 + o] + f_lds[(64 + li) * 17 + o]
                  + f_lds[(128 + li) * 17 + o] + f_lds[(192 + li) * 17 + o];
        out[(base_item + li) * 17 + o] = tot * scale_lds[li];
    }
}

extern "C" void kernel_launch(void* const* d_in, const int* in_sizes, int n_in,
                              void* d_out, int out_size, void* d_ws, size_t ws_size,
                              hipStream_t stream) {
    (void)in_sizes; (void)n_in; (void)out_size; (void)ws_size;
    const float* obs  = (const float*)d_in[0];
    const float* act  = (const float*)d_in[1];
    const float* ts   = (const float*)d_in[2];
    const float* Wih0 = (const float*)d_in[3];
    const float* Whh0 = (const float*)d_in[4];
    const float* bih0 = (const float*)d_in[5];
    const float* bhh0 = (const float*)d_in[6];
    const float* Wih1 = (const float*)d_in[7];
    const float* Whh1 = (const float*)d_in[8];
    const float* bih1 = (const float*)d_in[9];
    const float* bhh1 = (const float*)d_in[10];
    const float* encW = (const float*)d_in[11];
    const float* encb = (const float*)d_in[12];
    const float* W1   = (const float*)d_in[13];
    const float* b1   = (const float*)d_in[14];
    const float* W2   = (const float*)d_in[15];
    const float* b2   = (const float*)d_in[16];
    const float* W3   = (const float*)d_in[17];
    const float* b3   = (const float*)d_in[18];
    float* o_ptr  = (float*)d_out;
    float* p_act  = (float*)d_ws;   // 2048*2 floats scratch

    gru_kernel<<<dim3(512), dim3(128), 0, stream>>>(
        act, Wih0, Whh0, bih0, bhh0, Wih1, Whh1, bih1, bhh1, encW, encb, p_act);
    mlp_kernel<<<dim3(512), dim3(256), 0, stream>>>(
        obs, ts, p_act, W1, b1, W2, b2, W3, b3, o_ptr);
}

// Round 3
// 247.736 us; speedup vs baseline: 1.6302x; 1.6302x over previous
//
#include <hip/hip_runtime.h>
#include <math.h>

#define PI_F 3.14159265358979323846f

// ---------------- fast device math ----------------
__device__ __forceinline__ float sigm_f(float x) {
    return __fdividef(1.0f, 1.0f + __expf(-x));
}
__device__ __forceinline__ float tanh_f(float x) {
    float xc = fminf(fmaxf(x, -9.0f), 9.0f);
    float e = __expf(2.0f * xc);
    return 1.0f - __fdividef(2.0f, e + 1.0f);
}

// ---------------- macro lists ----------------
#define AP16(M) M(0) M(1) M(2) M(3) M(4) M(5) M(6) M(7) M(8) M(9) M(10) M(11) M(12) M(13) M(14) M(15)
#define AP64(M) AP16(M) M(16) M(17) M(18) M(19) M(20) M(21) M(22) M(23) \
  M(24) M(25) M(26) M(27) M(28) M(29) M(30) M(31) M(32) M(33) M(34) M(35) \
  M(36) M(37) M(38) M(39) M(40) M(41) M(42) M(43) M(44) M(45) M(46) M(47) \
  M(48) M(49) M(50) M(51) M(52) M(53) M(54) M(55) M(56) M(57) M(58) M(59) \
  M(60) M(61) M(62) M(63)
#define APQ16(M) M(0,1,2,3) M(4,5,6,7) M(8,9,10,11) M(12,13,14,15) \
  M(16,17,18,19) M(20,21,22,23) M(24,25,26,27) M(28,29,30,31) \
  M(32,33,34,35) M(36,37,38,39) M(40,41,42,43) M(44,45,46,47) \
  M(48,49,50,51) M(52,53,54,55) M(56,57,58,59) M(60,61,62,63)

// ============================================================
// Kernel 1: 2-layer GRU over reversed action sequence + encoder head.
// ============================================================
__global__ __launch_bounds__(128)
void gru_kernel(const float* __restrict__ act,
                const float* __restrict__ Wih0, const float* __restrict__ Whh0,
                const float* __restrict__ bih0, const float* __restrict__ bhh0,
                const float* __restrict__ Wih1, const float* __restrict__ Whh1,
                const float* __restrict__ bih1, const float* __restrict__ bhh1,
                const float* __restrict__ encW, const float* __restrict__ encb,
                float* __restrict__ p_out)
{
    __shared__ float wih0_l[6 * 96];
    __shared__ float whh0_l[32 * 96];
    __shared__ float wih1_l[32 * 96];
    __shared__ float whh1_l[32 * 96];
    __shared__ float enc_l[64];
    __shared__ float xbuf[4 * 32 * 6];
    __shared__ float hbuf0[4][32];
    __shared__ float hbuf1[4][32];

    const int tid = threadIdx.x;

    for (int idx = tid; idx < 96 * 6; idx += 128) {
        int r = idx / 6, c = idx - r * 6;
        wih0_l[c * 96 + (r & 31) * 3 + (r >> 5)] = Wih0[idx];
    }
    for (int idx = tid; idx < 96 * 32; idx += 128) {
        int r = idx >> 5, c = idx & 31;
        int d = c * 96 + (r & 31) * 3 + (r >> 5);
        whh0_l[d] = Whh0[idx];
        wih1_l[d] = Wih1[idx];
        whh1_l[d] = Whh1[idx];
    }
    if (tid < 64) {
        int o = tid >> 5, j = tid & 31;
        enc_l[j * 2 + o] = encW[o * 32 + j];
    }
    {
        const float inv3 = (1.0f / 3.0f);
        int base = blockIdx.x * (4 * 32 * 6);
        for (int idx = tid; idx < 4 * 32 * 6; idx += 128)
            xbuf[idx] = act[base + idx] * inv3;
    }
    __syncthreads();

    const int s = tid >> 5;
    const int j = tid & 31;
    const int b = blockIdx.x * 4 + s;
    const int j3 = j * 3;

    const float bi0r = bih0[j], bi0z = bih0[32 + j], bi0n = bih0[64 + j];
    const float bh0r = bhh0[j], bh0z = bhh0[32 + j], bh0n = bhh0[64 + j];
    const float bi1r = bih1[j], bi1z = bih1[32 + j], bi1n = bih1[64 + j];
    const float bh1r = bhh1[j], bh1z = bhh1[32 + j], bh1n = bhh1[64 + j];

    float* hb0 = &hbuf0[s][0];
    float* hb1 = &hbuf1[s][0];
    hb0[j] = 0.0f;
    hb1[j] = 0.0f;
    float h0 = 0.0f, h1 = 0.0f;
    const float* xs = &xbuf[s * 192];

    for (int t = 0; t < 32; ++t) {
        const float* xt = &xs[(31 - t) * 6];

        float ar = bi0r, az = bi0z, an = bi0n;
        #pragma unroll
        for (int d = 0; d < 6; ++d) {
            float xv = xt[d];
            const float* w = &wih0_l[d * 96 + j3];
            ar = fmaf(xv, w[0], ar); az = fmaf(xv, w[1], az); an = fmaf(xv, w[2], an);
        }
        float gr0 = bh0r, gz0 = bh0z, gn0 = bh0n;
        float gr1 = 0.0f, gz1 = 0.0f, gn1 = 0.0f;
        #pragma unroll
        for (int i = 0; i < 32; i += 2) {
            float hi0 = hb0[i], hi1 = hb0[i + 1];
            const float* w0 = &whh0_l[i * 96 + j3];
            const float* w1 = &whh0_l[(i + 1) * 96 + j3];
            gr0 = fmaf(hi0, w0[0], gr0); gz0 = fmaf(hi0, w0[1], gz0); gn0 = fmaf(hi0, w0[2], gn0);
            gr1 = fmaf(hi1, w1[0], gr1); gz1 = fmaf(hi1, w1[1], gz1); gn1 = fmaf(hi1, w1[2], gn1);
        }
        float r = sigm_f(ar + gr0 + gr1);
        float z = sigm_f(az + gz0 + gz1);
        float n = tanh_f(an + r * (gn0 + gn1));
        h0 = (1.0f - z) * n + z * h0;
        hb0[j] = h0;

        float a1r0 = bi1r, a1z0 = bi1z, a1n0 = bi1n;
        float a1r1 = 0.0f, a1z1 = 0.0f, a1n1 = 0.0f;
        #pragma unroll
        for (int i = 0; i < 32; i += 2) {
            float hi0 = hb0[i], hi1 = hb0[i + 1];
            const float* w0 = &wih1_l[i * 96 + j3];
            const float* w1 = &wih1_l[(i + 1) * 96 + j3];
            a1r0 = fmaf(hi0, w0[0], a1r0); a1z0 = fmaf(hi0, w0[1], a1z0); a1n0 = fmaf(hi0, w0[2], a1n0);
            a1r1 = fmaf(hi1, w1[0], a1r1); a1z1 = fmaf(hi1, w1[1], a1z1); a1n1 = fmaf(hi1, w1[2], a1n1);
        }
        float g1r0 = bh1r, g1z0 = bh1z, g1n0 = bh1n;
        float g1r1 = 0.0f, g1z1 = 0.0f, g1n1 = 0.0f;
        #pragma unroll
        for (int i = 0; i < 32; i += 2) {
            float hi0 = hb1[i], hi1 = hb1[i + 1];
            const float* w0 = &whh1_l[i * 96 + j3];
            const float* w1 = &whh1_l[(i + 1) * 96 + j3];
            g1r0 = fmaf(hi0, w0[0], g1r0); g1z0 = fmaf(hi0, w0[1], g1z0); g1n0 = fmaf(hi0, w0[2], g1n0);
            g1r1 = fmaf(hi1, w1[0], g1r1); g1z1 = fmaf(hi1, w1[1], g1z1); g1n1 = fmaf(hi1, w1[2], g1n1);
        }
        float r1 = sigm_f(a1r0 + a1r1 + g1r0 + g1r1);
        float z1 = sigm_f(a1z0 + a1z1 + g1z0 + g1z1);
        float n1 = tanh_f(a1n0 + a1n1 + r1 * (g1n0 + g1n1));
        h1 = (1.0f - z1) * n1 + z1 * h1;
        hb1[j] = h1;
    }

    float v0 = h1 * enc_l[j * 2 + 0];
    float v1 = h1 * enc_l[j * 2 + 1];
    #pragma unroll
    for (int off = 16; off > 0; off >>= 1) {
        v0 += __shfl_xor(v0, off, 32);
        v1 += __shfl_xor(v1, off, 32);
    }
    if (j == 0) {
        p_out[b * 2 + 0] = v0 + encb[0];
        p_out[b * 2 + 1] = v1 + encb[1];
    }
}

// ============================================================
// Kernel 2: per-(b,t) MLP + Laplace series. Named-VGPR activations,
// wave-uniform (SGPR) weights via readfirstlane(wave-id).
// ============================================================
__global__ __launch_bounds__(256, 2)
void mlp_kernel(const float* __restrict__ obs, const float* __restrict__ ts,
                const float* __restrict__ p_act,
                const float* __restrict__ W1, const float* __restrict__ b1,
                const float* __restrict__ W2, const float* __restrict__ b2,
                const float* __restrict__ W3, const float* __restrict__ b3,
                float* __restrict__ out)
{
    __shared__ float h1_lds[64 * 64];
    __shared__ float h2_lds[64 * 64];
    __shared__ float f_lds[4 * 64 * 17];
    __shared__ float scale_lds[64];

    const int tid = threadIdx.x;
    const int wq = __builtin_amdgcn_readfirstlane(tid >> 6);  // wave id (SGPR)
    const int l = tid & 63;
    const int item = blockIdx.x * 64 + l;
    const int b = item >> 4;
    const int obase = wq * 16;

    const float t = ts[item];
    const float rTc = __fdividef(0.5f, t);
    const float gamma = 0.001f + 4.6051701859880913680f * rTc;  // -ln(0.01)/Tc

    if (wq == 3) scale_lds[l] = __expf(gamma * t) * rTc;

    // ---- H1: i-outer, theta/phi on the fly, 16 named accumulators ----
    const float gam2 = gamma * gamma;
    const float rg = __fdividef(1.0f, gamma);
    const float pirTc = PI_F * rTc;

    #define DECL_ACC(o) float acc##o = b1[obase + o];
    AP16(DECL_ACC)
    #undef DECL_ACC

    {
        const float* wth = W1 + obase * 85;
        float fk = 0.0f;
        for (int k = 0; k < 33; ++k) {
            float sim = fk * pirTc;
            float vth = atanf(sim * rg);
            float sq = fmaf(sim, sim, gam2);
            float vph = asinf(__fdividef(sq - 1.0f, sq + 1.0f));
            const float* ct = wth + k;
            const float* cp = wth + 33 + k;
            #define H1C(o) acc##o = fmaf(vth, ct[(o) * 85], acc##o); \
                           acc##o = fmaf(vph, cp[(o) * 85], acc##o);
            AP16(H1C)
            #undef H1C
            fk += 1.0f;
        }
        const float* cpp = wth + 66;
        #pragma unroll
        for (int j = 0; j < 19; ++j) {
            float pv = (j < 17) ? obs[b * 17 + j] : p_act[b * 2 + (j - 17)];
            #define H1P(o) acc##o = fmaf(pv, cpp[(o) * 85 + j], acc##o);
            AP16(H1P)
            #undef H1P
        }
    }
    #define H1S(o) h1_lds[(obase + (o)) * 64 + l] = tanh_f(acc##o);
    AP16(H1S)
    #undef H1S
    __syncthreads();

    // ---- H2: h1 in 64 named regs ----
    {
        #define DH(i) float h##i = h1_lds[(i) * 64 + l];
        AP64(DH)
        #undef DH
        asm volatile("" : "+v"(h0),"+v"(h1),"+v"(h2),"+v"(h3),"+v"(h4),"+v"(h5),"+v"(h6),"+v"(h7),
                          "+v"(h8),"+v"(h9),"+v"(h10),"+v"(h11),"+v"(h12),"+v"(h13),"+v"(h14),"+v"(h15));
        asm volatile("" : "+v"(h16),"+v"(h17),"+v"(h18),"+v"(h19),"+v"(h20),"+v"(h21),"+v"(h22),"+v"(h23),
                          "+v"(h24),"+v"(h25),"+v"(h26),"+v"(h27),"+v"(h28),"+v"(h29),"+v"(h30),"+v"(h31));
        asm volatile("" : "+v"(h32),"+v"(h33),"+v"(h34),"+v"(h35),"+v"(h36),"+v"(h37),"+v"(h38),"+v"(h39),
                          "+v"(h40),"+v"(h41),"+v"(h42),"+v"(h43),"+v"(h44),"+v"(h45),"+v"(h46),"+v"(h47));
        asm volatile("" : "+v"(h48),"+v"(h49),"+v"(h50),"+v"(h51),"+v"(h52),"+v"(h53),"+v"(h54),"+v"(h55),
                          "+v"(h56),"+v"(h57),"+v"(h58),"+v"(h59),"+v"(h60),"+v"(h61),"+v"(h62),"+v"(h63));

        for (int oo = 0; oo < 16; ++oo) {
            const float* wr = W2 + (obase + oo) * 64;
            float ac0 = b2[obase + oo], ac1 = 0.0f, ac2 = 0.0f, ac3 = 0.0f;
            #define H2Q(i0,i1,i2,i3) ac0 = fmaf(h##i0, wr[i0], ac0); ac1 = fmaf(h##i1, wr[i1], ac1); \
                                     ac2 = fmaf(h##i2, wr[i2], ac2); ac3 = fmaf(h##i3, wr[i3], ac3);
            APQ16(H2Q)
            #undef H2Q
            h2_lds[(obase + oo) * 64 + l] = tanh_f((ac0 + ac1) + (ac2 + ac3));
        }
    }
    __syncthreads();

    // ---- W3 + series epilogue for k ≡ wq (mod 4) ----
    {
        #define DG(i) float g##i = h2_lds[(i) * 64 + l];
        AP64(DG)
        #undef DG
        asm volatile("" : "+v"(g0),"+v"(g1),"+v"(g2),"+v"(g3),"+v"(g4),"+v"(g5),"+v"(g6),"+v"(g7),
                          "+v"(g8),"+v"(g9),"+v"(g10),"+v"(g11),"+v"(g12),"+v"(g13),"+v"(g14),"+v"(g15));
        asm volatile("" : "+v"(g16),"+v"(g17),"+v"(g18),"+v"(g19),"+v"(g20),"+v"(g21),"+v"(g22),"+v"(g23),
                          "+v"(g24),"+v"(g25),"+v"(g26),"+v"(g27),"+v"(g28),"+v"(g29),"+v"(g30),"+v"(g31));
        asm volatile("" : "+v"(g32),"+v"(g33),"+v"(g34),"+v"(g35),"+v"(g36),"+v"(g37),"+v"(g38),"+v"(g39),
                          "+v"(g40),"+v"(g41),"+v"(g42),"+v"(g43),"+v"(g44),"+v"(g45),"+v"(g46),"+v"(g47));
        asm volatile("" : "+v"(g48),"+v"(g49),"+v"(g50),"+v"(g51),"+v"(g52),"+v"(g53),"+v"(g54),"+v"(g55),
                          "+v"(g56),"+v"(g57),"+v"(g58),"+v"(g59),"+v"(g60),"+v"(g61),"+v"(g62),"+v"(g63));

        const float csgn = (wq == 1 || wq == 2) ? -1.0f : 1.0f;
        for (int o = 0; o < 17; ++o) {
            float facc = 0.0f;
            for (int k = wq; k < 33; k += 4) {
                const int rt = o * 33 + k;
                const float* wt = W3 + rt * 64;
                const float* wp = W3 + (rt + 561) * 64;
                float at0 = 0.0f, at1 = 0.0f, at2 = 0.0f, at3 = 0.0f;
                float ap0 = 0.0f, ap1 = 0.0f, ap2 = 0.0f, ap3 = 0.0f;
                #define W3Q(i0,i1,i2,i3) \
                    at0 = fmaf(g##i0, wt[i0], at0); ap0 = fmaf(g##i0, wp[i0], ap0); \
                    at1 = fmaf(g##i1, wt[i1], at1); ap1 = fmaf(g##i1, wp[i1], ap1); \
                    at2 = fmaf(g##i2, wt[i2], at2); ap2 = fmaf(g##i2, wp[i2], ap2); \
                    at3 = fmaf(g##i3, wt[i3], at3); ap3 = fmaf(g##i3, wp[i3], ap3);
                APQ16(W3Q)
                #undef W3Q
                float at = b3[rt] + ((at0 + at1) + (at2 + at3));
                float ap = b3[rt + 561] + ((ap0 + ap1) + (ap2 + ap3));
                float theta = tanh_f(at) * PI_F;
                float phi   = tanh_f(ap) * (0.5f * PI_F);
                float sph = __sinf(phi), cph = __cosf(phi);
                float rd = __fdividef(1.0f, 1.0f - sph);
                float tr = (wq == 0 || wq == 2) ? __cosf(theta) : __sinf(theta);
                float wk = (k == 0) ? 0.5f : 1.0f;
                facc = fmaf(csgn * wk, tr * cph * rd, facc);
            }
            f_lds[(wq * 64 + l) * 17 + o] = facc;
        }
    }
    __syncthreads();

    // ---- reduce 4 k-class partials, scale, write out ----
    const int base_item = blockIdx.x * 64;
    for (int idx = tid; idx < 64 * 17; idx += 256) {
        const int li = idx / 17;
        const int o  = idx - li * 17;
        float tot = f_lds[li * 17 + o] + f_lds[(64 + li) * 17 + o]
                  + f_lds[(128 + li) * 17 + o] + f_lds[(192 + li) * 17 + o];
        out[(base_item + li) * 17 + o] = tot * scale_lds[li];
    }
}

extern "C" void kernel_launch(void* const* d_in, const int* in_sizes, int n_in,
                              void* d_out, int out_size, void* d_ws, size_t ws_size,
                              hipStream_t stream) {
    (void)in_sizes; (void)n_in; (void)out_size; (void)ws_size;
    const float* obs  = (const float*)d_in[0];
    const float* act  = (const float*)d_in[1];
    const float* ts   = (const float*)d_in[2];
    const float* Wih0 = (const float*)d_in[3];
    const float* Whh0 = (const float*)d_in[4];
    const float* bih0 = (const float*)d_in[5];
    const float* bhh0 = (const float*)d_in[6];
    const float* Wih1 = (const float*)d_in[7];
    const float* Whh1 = (const float*)d_in[8];
    const float* bih1 = (const float*)d_in[9];
    const float* bhh1 = (const float*)d_in[10];
    const float* encW = (const float*)d_in[11];
    const float* encb = (const float*)d_in[12];
    const float* W1   = (const float*)d_in[13];
    const float* b1   = (const float*)d_in[14];
    const float* W2   = (const float*)d_in[15];
    const float* b2   = (const float*)d_in[16];
    const float* W3   = (const float*)d_in[17];
    const float* b3   = (const float*)d_in[18];
    float* o_ptr  = (float*)d_out;
    float* p_act  = (float*)d_ws;

    gru_kernel<<<dim3(512), dim3(128), 0, stream>>>(
        act, Wih0, Whh0, bih0, bhh0, Wih1, Whh1, bih1, bhh1, encW, encb, p_act);
    mlp_kernel<<<dim3(512), dim3(256), 0, stream>>>(
        obs, ts, p_act, W1, b1, W2, b2, W3, b3, o_ptr);
}

// Round 4
// 246.625 us; speedup vs baseline: 1.6376x; 1.0045x over previous
//
#include <hip/hip_runtime.h>
#include <math.h>

#define PI_F 3.14159265358979323846f

// ---------------- fast device math ----------------
__device__ __forceinline__ float sigm_f(float x) {
    return __fdividef(1.0f, 1.0f + __expf(-x));
}
__device__ __forceinline__ float tanh_f(float x) {
    float xc = fminf(fmaxf(x, -9.0f), 9.0f);
    float e = __expf(2.0f * xc);
    return 1.0f - __fdividef(2.0f, e + 1.0f);
}

// ---------------- macro lists ----------------
#define AP16(M) M(0) M(1) M(2) M(3) M(4) M(5) M(6) M(7) M(8) M(9) M(10) M(11) M(12) M(13) M(14) M(15)
#define AP64(M) AP16(M) M(16) M(17) M(18) M(19) M(20) M(21) M(22) M(23) \
  M(24) M(25) M(26) M(27) M(28) M(29) M(30) M(31) M(32) M(33) M(34) M(35) \
  M(36) M(37) M(38) M(39) M(40) M(41) M(42) M(43) M(44) M(45) M(46) M(47) \
  M(48) M(49) M(50) M(51) M(52) M(53) M(54) M(55) M(56) M(57) M(58) M(59) \
  M(60) M(61) M(62) M(63)
#define APQ16(M) M(0,1,2,3) M(4,5,6,7) M(8,9,10,11) M(12,13,14,15) \
  M(16,17,18,19) M(20,21,22,23) M(24,25,26,27) M(28,29,30,31) \
  M(32,33,34,35) M(36,37,38,39) M(40,41,42,43) M(44,45,46,47) \
  M(48,49,50,51) M(52,53,54,55) M(56,57,58,59) M(60,61,62,63)

// ============================================================
// Kernel 1: 2-layer GRU over reversed action sequence + encoder head.
// ============================================================
__global__ __launch_bounds__(128)
void gru_kernel(const float* __restrict__ act,
                const float* __restrict__ Wih0, const float* __restrict__ Whh0,
                const float* __restrict__ bih0, const float* __restrict__ bhh0,
                const float* __restrict__ Wih1, const float* __restrict__ Whh1,
                const float* __restrict__ bih1, const float* __restrict__ bhh1,
                const float* __restrict__ encW, const float* __restrict__ encb,
                float* __restrict__ p_out)
{
    __shared__ float wih0_l[6 * 96];
    __shared__ float whh0_l[32 * 96];
    __shared__ float wih1_l[32 * 96];
    __shared__ float whh1_l[32 * 96];
    __shared__ float enc_l[64];
    __shared__ float xbuf[4 * 32 * 6];
    __shared__ float hbuf0[4][32];
    __shared__ float hbuf1[4][32];

    const int tid = threadIdx.x;

    for (int idx = tid; idx < 96 * 6; idx += 128) {
        int r = idx / 6, c = idx - r * 6;
        wih0_l[c * 96 + (r & 31) * 3 + (r >> 5)] = Wih0[idx];
    }
    for (int idx = tid; idx < 96 * 32; idx += 128) {
        int r = idx >> 5, c = idx & 31;
        int d = c * 96 + (r & 31) * 3 + (r >> 5);
        whh0_l[d] = Whh0[idx];
        wih1_l[d] = Wih1[idx];
        whh1_l[d] = Whh1[idx];
    }
    if (tid < 64) {
        int o = tid >> 5, j = tid & 31;
        enc_l[j * 2 + o] = encW[o * 32 + j];
    }
    {
        const float inv3 = (1.0f / 3.0f);
        int base = blockIdx.x * (4 * 32 * 6);
        for (int idx = tid; idx < 4 * 32 * 6; idx += 128)
            xbuf[idx] = act[base + idx] * inv3;
    }
    __syncthreads();

    const int s = tid >> 5;
    const int j = tid & 31;
    const int b = blockIdx.x * 4 + s;
    const int j3 = j * 3;

    const float bi0r = bih0[j], bi0z = bih0[32 + j], bi0n = bih0[64 + j];
    const float bh0r = bhh0[j], bh0z = bhh0[32 + j], bh0n = bhh0[64 + j];
    const float bi1r = bih1[j], bi1z = bih1[32 + j], bi1n = bih1[64 + j];
    const float bh1r = bhh1[j], bh1z = bhh1[32 + j], bh1n = bhh1[64 + j];

    float* hb0 = &hbuf0[s][0];
    float* hb1 = &hbuf1[s][0];
    hb0[j] = 0.0f;
    hb1[j] = 0.0f;
    float h0 = 0.0f, h1 = 0.0f;
    const float* xs = &xbuf[s * 192];

    for (int t = 0; t < 32; ++t) {
        const float* xt = &xs[(31 - t) * 6];

        float ar = bi0r, az = bi0z, an = bi0n;
        #pragma unroll
        for (int d = 0; d < 6; ++d) {
            float xv = xt[d];
            const float* w = &wih0_l[d * 96 + j3];
            ar = fmaf(xv, w[0], ar); az = fmaf(xv, w[1], az); an = fmaf(xv, w[2], an);
        }
        float gr0 = bh0r, gz0 = bh0z, gn0 = bh0n;
        float gr1 = 0.0f, gz1 = 0.0f, gn1 = 0.0f;
        #pragma unroll
        for (int i = 0; i < 32; i += 2) {
            float hi0 = hb0[i], hi1 = hb0[i + 1];
            const float* w0 = &whh0_l[i * 96 + j3];
            const float* w1 = &whh0_l[(i + 1) * 96 + j3];
            gr0 = fmaf(hi0, w0[0], gr0); gz0 = fmaf(hi0, w0[1], gz0); gn0 = fmaf(hi0, w0[2], gn0);
            gr1 = fmaf(hi1, w1[0], gr1); gz1 = fmaf(hi1, w1[1], gz1); gn1 = fmaf(hi1, w1[2], gn1);
        }
        float r = sigm_f(ar + gr0 + gr1);
        float z = sigm_f(az + gz0 + gz1);
        float n = tanh_f(an + r * (gn0 + gn1));
        h0 = (1.0f - z) * n + z * h0;
        hb0[j] = h0;

        float a1r0 = bi1r, a1z0 = bi1z, a1n0 = bi1n;
        float a1r1 = 0.0f, a1z1 = 0.0f, a1n1 = 0.0f;
        #pragma unroll
        for (int i = 0; i < 32; i += 2) {
            float hi0 = hb0[i], hi1 = hb0[i + 1];
            const float* w0 = &wih1_l[i * 96 + j3];
            const float* w1 = &wih1_l[(i + 1) * 96 + j3];
            a1r0 = fmaf(hi0, w0[0], a1r0); a1z0 = fmaf(hi0, w0[1], a1z0); a1n0 = fmaf(hi0, w0[2], a1n0);
            a1r1 = fmaf(hi1, w1[0], a1r1); a1z1 = fmaf(hi1, w1[1], a1z1); a1n1 = fmaf(hi1, w1[2], a1n1);
        }
        float g1r0 = bh1r, g1z0 = bh1z, g1n0 = bh1n;
        float g1r1 = 0.0f, g1z1 = 0.0f, g1n1 = 0.0f;
        #pragma unroll
        for (int i = 0; i < 32; i += 2) {
            float hi0 = hb1[i], hi1 = hb1[i + 1];
            const float* w0 = &whh1_l[i * 96 + j3];
            const float* w1 = &whh1_l[(i + 1) * 96 + j3];
            g1r0 = fmaf(hi0, w0[0], g1r0); g1z0 = fmaf(hi0, w0[1], g1z0); g1n0 = fmaf(hi0, w0[2], g1n0);
            g1r1 = fmaf(hi1, w1[0], g1r1); g1z1 = fmaf(hi1, w1[1], g1z1); g1n1 = fmaf(hi1, w1[2], g1n1);
        }
        float r1 = sigm_f(a1r0 + a1r1 + g1r0 + g1r1);
        float z1 = sigm_f(a1z0 + a1z1 + g1z0 + g1z1);
        float n1 = tanh_f(a1n0 + a1n1 + r1 * (g1n0 + g1n1));
        h1 = (1.0f - z1) * n1 + z1 * h1;
        hb1[j] = h1;
    }

    float v0 = h1 * enc_l[j * 2 + 0];
    float v1 = h1 * enc_l[j * 2 + 1];
    #pragma unroll
    for (int off = 16; off > 0; off >>= 1) {
        v0 += __shfl_xor(v0, off, 32);
        v1 += __shfl_xor(v1, off, 32);
    }
    if (j == 0) {
        p_out[b * 2 + 0] = v0 + encb[0];
        p_out[b * 2 + 1] = v1 + encb[1];
    }
}

// ============================================================
// Kernel 2: per-(b,t) MLP + Laplace series. Named-VGPR activations,
// wave-uniform (SGPR) weights via readfirstlane(wave-id).
// ============================================================
__global__ __launch_bounds__(256, 2)
void mlp_kernel(const float* __restrict__ obs, const float* __restrict__ ts,
                const float* __restrict__ p_act,
                const float* __restrict__ W1, const float* __restrict__ b1,
                const float* __restrict__ W2, const float* __restrict__ b2,
                const float* __restrict__ W3, const float* __restrict__ b3,
                float* __restrict__ out)
{
    __shared__ float h1_lds[64 * 64];
    __shared__ float h2_lds[64 * 64];
    __shared__ float f_lds[4 * 64 * 17];
    __shared__ float scale_lds[64];

    const int tid = threadIdx.x;
    const int wq = __builtin_amdgcn_readfirstlane(tid >> 6);  // wave id (SGPR)
    const int l = tid & 63;
    const int item = blockIdx.x * 64 + l;
    const int b = item >> 4;
    const int obase = wq * 16;

    const float t = ts[item];
    const float rTc = __fdividef(0.5f, t);
    const float gamma = 0.001f + 4.6051701859880913680f * rTc;  // -ln(0.01)/Tc

    if (wq == 3) scale_lds[l] = __expf(gamma * t) * rTc;

    // ---- H1: i-outer, theta/phi on the fly, 16 named accumulators ----
    const float gam2 = gamma * gamma;
    const float rg = __fdividef(1.0f, gamma);
    const float pirTc = PI_F * rTc;

    #define DECL_ACC(o) float acc##o = b1[obase + o];
    AP16(DECL_ACC)
    #undef DECL_ACC

    {
        const float* wth = W1 + obase * 85;
        float fk = 0.0f;
        for (int k = 0; k < 33; ++k) {
            float sim = fk * pirTc;
            float vth = atanf(sim * rg);
            float sq = fmaf(sim, sim, gam2);
            float vph = asinf(__fdividef(sq - 1.0f, sq + 1.0f));
            const float* ct = wth + k;
            const float* cp = wth + 33 + k;
            #define H1C(o) acc##o = fmaf(vth, ct[(o) * 85], acc##o); \
                           acc##o = fmaf(vph, cp[(o) * 85], acc##o);
            AP16(H1C)
            #undef H1C
            fk += 1.0f;
        }
        const float* cpp = wth + 66;
        #pragma unroll
        for (int j = 0; j < 19; ++j) {
            float pv = (j < 17) ? obs[b * 17 + j] : p_act[b * 2 + (j - 17)];
            #define H1P(o) acc##o = fmaf(pv, cpp[(o) * 85 + j], acc##o);
            AP16(H1P)
            #undef H1P
        }
    }
    #define H1S(o) h1_lds[(obase + (o)) * 64 + l] = tanh_f(acc##o);
    AP16(H1S)
    #undef H1S
    __syncthreads();

    // ---- H2: h1 in 64 named regs ----
    {
        #define DH(i) float h##i = h1_lds[(i) * 64 + l];
        AP64(DH)
        #undef DH
        asm volatile("" : "+v"(h0),"+v"(h1),"+v"(h2),"+v"(h3),"+v"(h4),"+v"(h5),"+v"(h6),"+v"(h7),
                          "+v"(h8),"+v"(h9),"+v"(h10),"+v"(h11),"+v"(h12),"+v"(h13),"+v"(h14),"+v"(h15));
        asm volatile("" : "+v"(h16),"+v"(h17),"+v"(h18),"+v"(h19),"+v"(h20),"+v"(h21),"+v"(h22),"+v"(h23),
                          "+v"(h24),"+v"(h25),"+v"(h26),"+v"(h27),"+v"(h28),"+v"(h29),"+v"(h30),"+v"(h31));
        asm volatile("" : "+v"(h32),"+v"(h33),"+v"(h34),"+v"(h35),"+v"(h36),"+v"(h37),"+v"(h38),"+v"(h39),
                          "+v"(h40),"+v"(h41),"+v"(h42),"+v"(h43),"+v"(h44),"+v"(h45),"+v"(h46),"+v"(h47));
        asm volatile("" : "+v"(h48),"+v"(h49),"+v"(h50),"+v"(h51),"+v"(h52),"+v"(h53),"+v"(h54),"+v"(h55),
                          "+v"(h56),"+v"(h57),"+v"(h58),"+v"(h59),"+v"(h60),"+v"(h61),"+v"(h62),"+v"(h63));

        for (int oo = 0; oo < 16; ++oo) {
            const float* wr = W2 + (obase + oo) * 64;
            float ac0 = b2[obase + oo], ac1 = 0.0f, ac2 = 0.0f, ac3 = 0.0f;
            #define H2Q(i0,i1,i2,i3) ac0 = fmaf(h##i0, wr[i0], ac0); ac1 = fmaf(h##i1, wr[i1], ac1); \
                                     ac2 = fmaf(h##i2, wr[i2], ac2); ac3 = fmaf(h##i3, wr[i3], ac3);
            APQ16(H2Q)
            #undef H2Q
            h2_lds[(obase + oo) * 64 + l] = tanh_f((ac0 + ac1) + (ac2 + ac3));
        }
    }
    __syncthreads();

    // ---- W3 + series epilogue for k ≡ wq (mod 4) ----
    {
        #define DG(i) float g##i = h2_lds[(i) * 64 + l];
        AP64(DG)
        #undef DG
        asm volatile("" : "+v"(g0),"+v"(g1),"+v"(g2),"+v"(g3),"+v"(g4),"+v"(g5),"+v"(g6),"+v"(g7),
                          "+v"(g8),"+v"(g9),"+v"(g10),"+v"(g11),"+v"(g12),"+v"(g13),"+v"(g14),"+v"(g15));
        asm volatile("" : "+v"(g16),"+v"(g17),"+v"(g18),"+v"(g19),"+v"(g20),"+v"(g21),"+v"(g22),"+v"(g23),
                          "+v"(g24),"+v"(g25),"+v"(g26),"+v"(g27),"+v"(g28),"+v"(g29),"+v"(g30),"+v"(g31));
        asm volatile("" : "+v"(g32),"+v"(g33),"+v"(g34),"+v"(g35),"+v"(g36),"+v"(g37),"+v"(g38),"+v"(g39),
                          "+v"(g40),"+v"(g41),"+v"(g42),"+v"(g43),"+v"(g44),"+v"(g45),"+v"(g46),"+v"(g47));
        asm volatile("" : "+v"(g48),"+v"(g49),"+v"(g50),"+v"(g51),"+v"(g52),"+v"(g53),"+v"(g54),"+v"(g55),
                          "+v"(g56),"+v"(g57),"+v"(g58),"+v"(g59),"+v"(g60),"+v"(g61),"+v"(g62),"+v"(g63));

        const float csgn = (wq == 1 || wq == 2) ? -1.0f : 1.0f;
        for (int o = 0; o < 17; ++o) {
            float facc = 0.0f;
            for (int k = wq; k < 33; k += 4) {
                const int rt = o * 33 + k;
                const float* wt = W3 + rt * 64;
                const float* wp = W3 + (rt + 561) * 64;
                float at0 = 0.0f, at1 = 0.0f, at2 = 0.0f, at3 = 0.0f;
                float ap0 = 0.0f, ap1 = 0.0f, ap2 = 0.0f, ap3 = 0.0f;
                #define W3Q(i0,i1,i2,i3) \
                    at0 = fmaf(g##i0, wt[i0], at0); ap0 = fmaf(g##i0, wp[i0], ap0); \
                    at1 = fmaf(g##i1, wt[i1], at1); ap1 = fmaf(g##i1, wp[i1], ap1); \
                    at2 = fmaf(g##i2, wt[i2], at2); ap2 = fmaf(g##i2, wp[i2], ap2); \
                    at3 = fmaf(g##i3, wt[i3], at3); ap3 = fmaf(g##i3, wp[i3], ap3);
                APQ16(W3Q)
                #undef W3Q
                float at = b3[rt] + ((at0 + at1) + (at2 + at3));
                float ap = b3[rt + 561] + ((ap0 + ap1) + (ap2 + ap3));
                float theta = tanh_f(at) * PI_F;
                float phi   = tanh_f(ap) * (0.5f * PI_F);
                float sph = __sinf(phi), cph = __cosf(phi);
                float rd = __fdividef(1.0f, 1.0f - sph);
                float tr = (wq == 0 || wq == 2) ? __cosf(theta) : __sinf(theta);
                float wk = (k == 0) ? 0.5f : 1.0f;
                facc = fmaf(csgn * wk, tr * cph * rd, facc);
            }
            f_lds[(wq * 64 + l) * 17 + o] = facc;
        }
    }
    __syncthreads();

    // ---- reduce 4 k-class partials, scale, write out ----
    const int base_item = blockIdx.x * 64;
    for (int idx = tid; idx < 64 * 17; idx += 256) {
        const int li = idx / 17;
        const int o  = idx - li * 17;
        float tot = f_lds[li * 17 + o] + f_lds[(64 + li) * 17 + o]
                  + f_lds[(128 + li) * 17 + o] + f_lds[(192 + li) * 17 + o];
        out[(base_item + li) * 17 + o] = tot * scale_lds[li];
    }
}

extern "C" void kernel_launch(void* const* d_in, const int* in_sizes, int n_in,
                              void* d_out, int out_size, void* d_ws, size_t ws_size,
                              hipStream_t stream) {
    (void)in_sizes; (void)n_in; (void)out_size; (void)ws_size;
    const float* obs  = (const float*)d_in[0];
    const float* act  = (const float*)d_in[1];
    const float* ts   = (const float*)d_in[2];
    const float* Wih0 = (const float*)d_in[3];
    const float* Whh0 = (const float*)d_in[4];
    const float* bih0 = (const float*)d_in[5];
    const float* bhh0 = (const float*)d_in[6];
    const float* Wih1 = (const float*)d_in[7];
    const float* Whh1 = (const float*)d_in[8];
    const float* bih1 = (const float*)d_in[9];
    const float* bhh1 = (const float*)d_in[10];
    const float* encW = (const float*)d_in[11];
    const float* encb = (const float*)d_in[12];
    const float* W1   = (const float*)d_in[13];
    const float* b1   = (const float*)d_in[14];
    const float* W2   = (const float*)d_in[15];
    const float* b2   = (const float*)d_in[16];
    const float* W3   = (const float*)d_in[17];
    const float* b3   = (const float*)d_in[18];
    float* o_ptr  = (float*)d_out;
    float* p_act  = (float*)d_ws;

    gru_kernel<<<dim3(512), dim3(128), 0, stream>>>(
        act, Wih0, Whh0, bih0, bhh0, Wih1, Whh1, bih1, bhh1, encW, encb, p_act);
    mlp_kernel<<<dim3(512), dim3(256), 0, stream>>>(
        obs, ts, p_act, W1, b1, W2, b2, W3, b3, o_ptr);
}